// Round 2
// baseline (14670.587 us; speedup 1.0000x reference)
//
#include <hip/hip_runtime.h>
#include <stdint.h>

// Recursive Gaussian LSTM, persistent kernel, 32 WGs x 256 threads.
// R2 change vs R1: NO acquire/release fences (they emit buffer_wbl2/buffer_inv
// = full per-XCD L2 writeback/invalidate on gfx950 -> 478MB HBM refetch and
// ~14us/barrier). Exchange data (preh/prec/h/flags) now moves via RELAXED
// agent-scope atomics = global_load/store with sc0 sc1 (L3-direct, coherent,
// no cache maintenance). Ordering: per-wave s_waitcnt vmcnt(0) + syncthreads
// before the flag store. x/eps/weights/out stay plain cached accesses.
// Overlap: phase-A x-part before h-wait; eps prefetch before preh-wait.

#define NWG 32
#define UPW 8   // units per WG
#define T_STEPS 512
#define STRIDE_OUT 8388608ull  // B*T*HS

typedef float floatx4 __attribute__((ext_vector_type(4)));
typedef short bfx8 __attribute__((ext_vector_type(8)));

#define AT_LD(p)   __hip_atomic_load((p), __ATOMIC_RELAXED, __HIP_MEMORY_SCOPE_AGENT)
#define AT_ST(p,v) __hip_atomic_store((p), (v), __ATOMIC_RELAXED, __HIP_MEMORY_SCOPE_AGENT)

__device__ inline short f2bf(float f) {
  union { float f; uint32_t u; } v; v.f = f;
  uint32_t r = v.u + 0x7fffu + ((v.u >> 16) & 1u);  // RNE
  return (short)(r >> 16);
}
__device__ inline float sigm(float x) { return 1.f / (1.f + __expf(-x)); }
__device__ inline float tanhfast(float x) {
  float e = __expf(2.f * x);
  return 1.f - 2.f / (e + 1.f);
}
__device__ inline float softplusf(float x) {
  return (x > 15.f) ? x : log1pf(__expf(x));
}

// 16B coherent exchange ops: two 64-bit relaxed agent atomics (sc0 sc1, L3-direct)
__device__ inline bfx8 ld16_agent(const short* p) {
  union { bfx8 v; unsigned long long u[2]; } r;
  const unsigned long long* q = (const unsigned long long*)p;
  r.u[0] = AT_LD(q);
  r.u[1] = AT_LD(q + 1);
  return r.v;
}
__device__ inline void st16_agent(short* p, bfx8 v) {
  union { bfx8 v; unsigned long long u[2]; } r; r.v = v;
  unsigned long long* q = (unsigned long long*)p;
  AT_ST(q, r.u[0]);
  AT_ST(q + 1, r.u[1]);
}
__device__ inline void drain_stores() {
  asm volatile("s_waitcnt vmcnt(0)" ::: "memory");
}
// every wave spins on all 32 WG flags (no cache maintenance, pure L3 polls)
__device__ inline void wait_flags(const int* flags, int ep) {
  const int lane = threadIdx.x & 63;
  const int* p = flags + (lane & 31) * 16;
  int v;
  do {
    v = AT_LD(p);
    if (v < ep) __builtin_amdgcn_s_sleep(1);
  } while (__any(v < ep));
  asm volatile("" ::: "memory");  // compiler barrier: keep data loads after spin
}

__global__ __launch_bounds__(256, 1)
void glstm_kernel(const float* __restrict__ x,
                  const float* __restrict__ Wih,
                  const float* __restrict__ Whh,
                  const float* __restrict__ bias,
                  const float* __restrict__ Hrep,
                  const float* __restrict__ Crep,
                  const float* __restrict__ eps_h,
                  const float* __restrict__ eps_c,
                  float* __restrict__ out,
                  int* __restrict__ flagP,
                  int* __restrict__ flagH,
                  short* __restrict__ ht0,
                  short* __restrict__ ht1,
                  short* __restrict__ preh,
                  short* __restrict__ prec) {
  const int wg   = blockIdx.x;
  const int tid  = threadIdx.x;
  const int wave = tid >> 6;
  const int l    = tid & 63;
  const int n    = l & 15;
  const int quad = l >> 4;
  const bool act = (n < UPW);
  const int s    = wg * UPW + (act ? n : 0);

  __shared__ float xch[4][64][9];   // transpose buffer
  __shared__ short sp[64][18];      // pack buffer: [b][0..7]=preh|h, [8..15]=prec

  // ---------------- one-time: weights into registers as B-fragments ----------
  bfx8 Bg[16];   // gates K=512 (k<256 Wih else Whh), col = wave*256 + s
  bfx8 Br[8];    // reparam K=256, col = (wave&1)*256 + s in Hrep(wave<2)/Crep
  {
    const int gcol = wave * 256 + s;
    #pragma unroll
    for (int kt = 0; kt < 16; ++kt) {
      bfx8 r;
      #pragma unroll
      for (int j = 0; j < 8; ++j) {
        int k = kt * 32 + quad * 8 + j;
        float v = 0.f;
        if (act) v = (k < 256) ? Wih[k * 1024 + gcol] : Whh[(k - 256) * 1024 + gcol];
        r[j] = f2bf(v);
      }
      Bg[kt] = r;
    }
    const float* R = (wave < 2) ? Hrep : Crep;
    const int rcol = (wave & 1) * 256 + s;
    #pragma unroll
    for (int kt = 0; kt < 8; ++kt) {
      bfx8 r;
      #pragma unroll
      for (int j = 0; j < 8; ++j) {
        int k = kt * 32 + quad * 8 + j;
        float v = act ? R[k * 512 + rcol] : 0.f;
        r[j] = f2bf(v);
      }
      Br[kt] = r;
    }
  }
  float bi = 0.f, bfv = 0.f, bgv = 0.f, bov = 0.f;
  if (act) { bi = bias[s]; bfv = bias[256 + s]; bgv = bias[512 + s]; bov = bias[768 + s]; }
  float c_reg[4] = {0.f, 0.f, 0.f, 0.f};

  #pragma unroll 1
  for (int t = 0; t < T_STEPS; ++t) {
    const short* htr = (t & 1) ? ht1 : ht0;
    short* htw       = (t & 1) ? ht0 : ht1;

    // ---- phase A, x-part (no h dependency; runs before the h-ready wait) ----
    floatx4 acc[4];
    #pragma unroll
    for (int mt = 0; mt < 4; ++mt) acc[mt] = 0.f;
    #pragma unroll
    for (int kt = 0; kt < 8; ++kt) {
      bfx8 a[4];
      #pragma unroll
      for (int mt = 0; mt < 4; ++mt) {
        int b = mt * 16 + n;
        const floatx4* px = (const floatx4*)(x + ((size_t)(b * 512 + t)) * 256 + kt * 32 + quad * 8);
        floatx4 lo = px[0], hi = px[1];
        bfx8 av;
        av[0] = f2bf(lo[0]); av[1] = f2bf(lo[1]); av[2] = f2bf(lo[2]); av[3] = f2bf(lo[3]);
        av[4] = f2bf(hi[0]); av[5] = f2bf(hi[1]); av[6] = f2bf(hi[2]); av[7] = f2bf(hi[3]);
        a[mt] = av;
      }
      #pragma unroll
      for (int mt = 0; mt < 4; ++mt)
        acc[mt] = __builtin_amdgcn_mfma_f32_16x16x32_bf16(a[mt], Bg[kt], acc[mt], 0, 0, 0);
    }

    // ---- wait h(t-1) ready, then phase A h-part via L3-coherent loads ----
    wait_flags(flagH, t);
    #pragma unroll
    for (int kt = 0; kt < 8; ++kt) {
      bfx8 a[4];
      #pragma unroll
      for (int mt = 0; mt < 4; ++mt)
        a[mt] = ld16_agent(htr + (mt * 16 + n) * 256 + kt * 32 + quad * 8);
      #pragma unroll
      for (int mt = 0; mt < 4; ++mt)
        acc[mt] = __builtin_amdgcn_mfma_f32_16x16x32_bf16(a[mt], Bg[8 + kt], acc[mt], 0, 0, 0);
    }

    // transpose D (row=quad*4+reg, col=n) via LDS
    if (act) {
      #pragma unroll
      for (int mt = 0; mt < 4; ++mt)
        #pragma unroll
        for (int r = 0; r < 4; ++r)
          xch[wave][mt * 16 + quad * 4 + r][n] = acc[mt][r];
    }
    __syncthreads();
    // activations -> pack pre_h/pre_c into LDS
    if (act) {
      #pragma unroll
      for (int r = 0; r < 4; ++r) {
        int b = wave * 16 + quad * 4 + r;
        float gi = sigm(xch[0][b][n] + bi);
        float gf = sigm(xch[1][b][n] + bfv);
        float gg = tanhfast(xch[2][b][n] + bgv);
        float go = sigm(xch[3][b][n] + bov);
        float pc = gf * c_reg[r] + gi * gg;
        float ph = go * tanhfast(c_reg[r]);   // OLD c
        sp[b][n]     = f2bf(ph);
        sp[b][8 + n] = f2bf(pc);
      }
    }
    __syncthreads();
    // cooperative coherent store: 16B contiguous per batch row (cols 8w..8w+7)
    if (tid < 128) {
      int b = tid & 63;
      const short* srow = (tid < 64) ? &sp[b][0] : &sp[b][8];
      bfx8 v;
      #pragma unroll
      for (int j = 0; j < 8; ++j) v[j] = srow[j];
      short* dst = ((tid < 64) ? preh : prec) + b * 256 + wg * UPW;
      st16_agent(dst, v);
    }
    drain_stores();
    __syncthreads();
    if (tid == 0) AT_ST(flagP + wg * 16, t + 1);

    // eps prefetch (plain cached loads) overlaps the preh-ready wait
    float ehv[4] = {0, 0, 0, 0}, ecv[4] = {0, 0, 0, 0};
    if (act) {
      #pragma unroll
      for (int r = 0; r < 4; ++r) {
        int b = wave * 16 + quad * 4 + r;
        ehv[r] = eps_h[((size_t)t * 64 + b) * 256 + s];
        ecv[r] = eps_c[((size_t)t * 64 + b) * 256 + s];
      }
    }
    wait_flags(flagP, t + 1);

    // ---- phase B: reparam GEMMs over all units (L3-coherent A reads) ----
    const short* pA = (wave < 2) ? preh : prec;
    floatx4 racc[4];
    #pragma unroll
    for (int mt = 0; mt < 4; ++mt) racc[mt] = 0.f;
    #pragma unroll
    for (int kt = 0; kt < 8; ++kt) {
      bfx8 a[4];
      #pragma unroll
      for (int mt = 0; mt < 4; ++mt)
        a[mt] = ld16_agent(pA + (mt * 16 + n) * 256 + kt * 32 + quad * 8);
      #pragma unroll
      for (int mt = 0; mt < 4; ++mt)
        racc[mt] = __builtin_amdgcn_mfma_f32_16x16x32_bf16(a[mt], Br[kt], racc[mt], 0, 0, 0);
    }
    if (act) {
      #pragma unroll
      for (int mt = 0; mt < 4; ++mt)
        #pragma unroll
        for (int r = 0; r < 4; ++r)
          xch[wave][mt * 16 + quad * 4 + r][n] = racc[mt][r];
    }
    __syncthreads();
    // sampling epilogue + outputs + pack h into LDS
    if (act) {
      #pragma unroll
      for (int r = 0; r < 4; ++r) {
        int b = wave * 16 + quad * 4 + r;
        float mh  = fminf(fmaxf(xch[0][b][n], 1e-6f), 1e6f);
        float sh  = fmaxf(softplusf(xch[1][b][n]), 1e-6f);
        float mc  = fminf(fmaxf(xch[2][b][n], 1e-6f), 1e6f);
        float scv = fmaxf(softplusf(xch[3][b][n]), 1e-6f);
        float hn = mh + ehv[r] * sh;
        float cn = mc + ecv[r] * scv;
        c_reg[r] = cn;
        sp[b][n] = f2bf(hn);
        size_t o = ((size_t)b * 512 + t) * 256 + s;
        out[o] = hn;
        out[STRIDE_OUT + o] = cn;
        out[2 * STRIDE_OUT + o] = mh;
        out[3 * STRIDE_OUT + o] = sh;
        out[4 * STRIDE_OUT + o] = mc;
        out[5 * STRIDE_OUT + o] = scv;
        if (t == T_STEPS - 1) {
          out[6 * STRIDE_OUT + (size_t)b * 256 + s] = hn;
          out[6 * STRIDE_OUT + 16384 + (size_t)b * 256 + s] = cn;
        }
      }
    }
    __syncthreads();
    if (tid < 64) {
      bfx8 v;
      #pragma unroll
      for (int j = 0; j < 8; ++j) v[j] = sp[tid][j];
      st16_agent(htw + tid * 256 + wg * UPW, v);
    }
    drain_stores();
    __syncthreads();
    if (tid == 0) AT_ST(flagH + wg * 16, t + 1);
  }
}

extern "C" void kernel_launch(void* const* d_in, const int* in_sizes, int n_in,
                              void* d_out, int out_size, void* d_ws, size_t ws_size,
                              hipStream_t stream) {
  const float* x    = (const float*)d_in[0];
  const float* Wih  = (const float*)d_in[1];
  const float* Whh  = (const float*)d_in[2];
  const float* bias = (const float*)d_in[3];
  const float* Hrep = (const float*)d_in[4];
  const float* Crep = (const float*)d_in[5];
  const float* eps_h = (const float*)d_in[6];
  const float* eps_c = (const float*)d_in[7];
  float* out = (float*)d_out;

  char* ws = (char*)d_ws;
  int*   flagP = (int*)ws;                    // 32 x 64B
  int*   flagH = (int*)(ws + 2048);           // 32 x 64B
  short* ht0   = (short*)(ws + 4096);         // zeroed: h(0)
  short* ht1   = (short*)(ws + 4096 + 32768);
  short* preh  = (short*)(ws + 4096 + 2 * 32768);
  short* prec  = (short*)(ws + 4096 + 3 * 32768);
  // zero flags + ht0 every launch (graph-capture safe)
  hipMemsetAsync(d_ws, 0, 4096 + 32768, stream);

  glstm_kernel<<<dim3(NWG), dim3(256), 0, stream>>>(
      x, Wih, Whh, bias, Hrep, Crep, eps_h, eps_c, out,
      flagP, flagH, ht0, ht1, preh, prec);
}